// Round 3
// baseline (17.392 us; speedup 1.0000x reference)
//
#include <hip/hip_runtime.h>
#include <hip/hip_bf16.h>

// Span-mean aggregation:
//   out[b,s,:] = (s < lengths[b]) ? mean(x[b, i0..j0), :]) : 0
//
// R3 structure: 1024 blocks x 192 threads; each block handles G=4 spans at
//   bs = blockIdx.x + g * gridDim.x   (stride mapping -> mixes valid/invalid
//   spans per block, balancing load; 4 independent span pipelines per wave
//   give 4x memory-level parallelism).
// Thread d owns float4 column d for every span it touches.

constexpr int G = 4;

__global__ __launch_bounds__(256) void span_mean_kernel(
        const float4* __restrict__ x,
        const int* __restrict__ lengths,
        const int* __restrict__ spans,
        float4* __restrict__ out,
        int BS, int S, int T, int D4) {
    const int d      = threadIdx.x;
    const int stride = gridDim.x;

    // Preload all block-uniform span metadata up front (independent scalar
    // loads, all in flight together).
    int bs[G], len[G], i0[G], n[G];
    bool act[G];
    #pragma unroll
    for (int g = 0; g < G; ++g) {
        bs[g]  = blockIdx.x + g * stride;
        act[g] = bs[g] < BS;
        if (act[g]) {
            const int b = bs[g] / S;
            len[g] = lengths[b];
            i0[g]  = spans[2 * bs[g] + 0];
            n[g]   = spans[2 * bs[g] + 1] - i0[g];
        }
    }

    if (d >= D4) return;

    #pragma unroll
    for (int g = 0; g < G; ++g) {
        if (!act[g]) continue;
        const int b = bs[g] / S;
        const int s = bs[g] - b * S;
        float4* __restrict__ o = out + (size_t)bs[g] * D4 + d;

        if (s >= len[g]) {
            *o = make_float4(0.f, 0.f, 0.f, 0.f);
            continue;
        }

        const float inv = 1.0f / (float)(n[g] > 1 ? n[g] : 1);
        const float4* __restrict__ p =
            x + ((size_t)b * T + i0[g]) * (size_t)D4 + d;

        float4 acc;
        if (n[g] == 8) {
            float4 v0 = p[0 * (size_t)D4];
            float4 v1 = p[1 * (size_t)D4];
            float4 v2 = p[2 * (size_t)D4];
            float4 v3 = p[3 * (size_t)D4];
            float4 v4 = p[4 * (size_t)D4];
            float4 v5 = p[5 * (size_t)D4];
            float4 v6 = p[6 * (size_t)D4];
            float4 v7 = p[7 * (size_t)D4];
            acc.x = ((v0.x + v1.x) + (v2.x + v3.x)) + ((v4.x + v5.x) + (v6.x + v7.x));
            acc.y = ((v0.y + v1.y) + (v2.y + v3.y)) + ((v4.y + v5.y) + (v6.y + v7.y));
            acc.z = ((v0.z + v1.z) + (v2.z + v3.z)) + ((v4.z + v5.z) + (v6.z + v7.z));
            acc.w = ((v0.w + v1.w) + (v2.w + v3.w)) + ((v4.w + v5.w) + (v6.w + v7.w));
        } else {
            acc = make_float4(0.f, 0.f, 0.f, 0.f);
            for (int k = 0; k < n[g]; ++k) {
                float4 v = p[(size_t)k * D4];
                acc.x += v.x; acc.y += v.y; acc.z += v.z; acc.w += v.w;
            }
        }
        *o = make_float4(acc.x * inv, acc.y * inv, acc.z * inv, acc.w * inv);
    }
}

extern "C" void kernel_launch(void* const* d_in, const int* in_sizes, int n_in,
                              void* d_out, int out_size, void* d_ws, size_t ws_size,
                              hipStream_t stream) {
    const float* x        = (const float*)d_in[0];   // (B, T, D) fp32
    const int*   lengths  = (const int*)d_in[1];     // (B,)
    const int*   spans    = (const int*)d_in[2];     // (B, S, 2)
    float*       out      = (float*)d_out;           // (B, S, D) fp32

    const int B  = in_sizes[1];
    const int S  = in_sizes[2] / (2 * B);
    const int D  = out_size / (B * S);
    const int T  = in_sizes[0] / (B * D);
    const int D4 = D / 4;                            // D=768 -> 192
    const int BS = B * S;                            // 4096

    int block = ((D4 + 63) / 64) * 64;               // 192 for D=768
    if (block > 256) block = 256;
    if (block < 64)  block = 64;

    const int grid = (BS + G - 1) / G;               // 1024

    span_mean_kernel<<<dim3(grid), dim3(block), 0, stream>>>(
        (const float4*)x, lengths, spans, (float4*)out, BS, S, T, D4);
}

// Round 4
// 16.165 us; speedup vs baseline: 1.0760x; 1.0760x over previous
//
#include <hip/hip_runtime.h>
#include <hip/hip_bf16.h>

// Span-mean aggregation:
//   out[b,s,:] = (s < lengths[b]) ? mean(x[b, start..end), :]) : 0
// B=8, T=4096, S=512, D=768 in the reference; sizes derived at launch.
//
// FINAL (revert to R1, best measured: 16.07 us):
// One block per (b,s). blockDim = D/4 lanes rounded to a wave multiple;
// each thread owns one float4 column slice, sums n<=8 rows, scales, stores.
//
// Journal: R1 16.07us / R2 (hoisted metadata + static unroll) 16.12us /
// R3 (G=4 spans per block, stride-mapped) 17.39us. Traffic floor ~63 MB
// (~50 MB valid reads + 12.6 MB writes) = ~10us at 6.3-6.5 TB/s; the
// remaining ~6us is graph-replay/launch/ramp overhead (structure-invariant
// across all three variants). Memory-bound; no byte can be removed.

__global__ void span_mean_kernel(const float4* __restrict__ x,
                                 const int* __restrict__ lengths,
                                 const int* __restrict__ spans,
                                 float4* __restrict__ out,
                                 int S, int T, int D4) {
    const int bs = blockIdx.x;          // b * S + s
    const int b  = bs / S;
    const int s  = bs - b * S;

    float4* __restrict__ o = out + (size_t)bs * D4;

    if (s >= lengths[b]) {
        // Invalid span: write zeros, skip input entirely.
        const float4 z = make_float4(0.f, 0.f, 0.f, 0.f);
        for (int d = threadIdx.x; d < D4; d += blockDim.x) o[d] = z;
        return;
    }

    const int i0 = spans[2 * bs + 0];
    const int j0 = spans[2 * bs + 1];
    const int n  = j0 - i0;
    const float inv = 1.0f / (float)(n > 1 ? n : 1);

    const float4* __restrict__ base = x + ((size_t)b * T + i0) * (size_t)D4;

    for (int d = threadIdx.x; d < D4; d += blockDim.x) {
        float4 acc = make_float4(0.f, 0.f, 0.f, 0.f);
        const float4* p = base + d;
        #pragma unroll 8
        for (int k = 0; k < n; ++k) {
            float4 v = p[(size_t)k * D4];
            acc.x += v.x; acc.y += v.y; acc.z += v.z; acc.w += v.w;
        }
        o[d] = make_float4(acc.x * inv, acc.y * inv, acc.z * inv, acc.w * inv);
    }
}

extern "C" void kernel_launch(void* const* d_in, const int* in_sizes, int n_in,
                              void* d_out, int out_size, void* d_ws, size_t ws_size,
                              hipStream_t stream) {
    const float* x        = (const float*)d_in[0];   // (B, T, D) fp32
    const int*   lengths  = (const int*)d_in[1];     // (B,)
    const int*   spans    = (const int*)d_in[2];     // (B, S, 2)
    float*       out      = (float*)d_out;           // (B, S, D) fp32

    const int B  = in_sizes[1];
    const int S  = in_sizes[2] / (2 * B);
    const int D  = out_size / (B * S);
    const int T  = in_sizes[0] / (B * D);
    const int D4 = D / 4;                            // D=768 -> 192

    // Block size: cover D4 lanes with whole waves, cap at 256.
    int block = ((D4 + 63) / 64) * 64;
    if (block > 256) block = 256;
    if (block < 64)  block = 64;

    dim3 grid(B * S);
    span_mean_kernel<<<grid, dim3(block), 0, stream>>>(
        (const float4*)x, lengths, spans, (float4*)out, S, T, D4);
}